// Round 4
// baseline (664.934 us; speedup 1.0000x reference)
//
#include <hip/hip_runtime.h>

typedef float f32x4 __attribute__((ext_vector_type(4)));
typedef short short8 __attribute__((ext_vector_type(8)));

// Problem constants
#define B_    32
#define NV_   2048
#define NS_   512
#define L_    64
#define FEAT_ 1024
#define SEM_  512
#define HID_  512
#define ATT_  512
#define DM_   512

#define FENCE asm volatile("" ::: "memory")

__device__ __forceinline__ unsigned int f2bf_pk(float lo, float hi) {
  unsigned int ul = (__float_as_uint(lo) + 0x8000u) >> 16;
  unsigned int uh = (__float_as_uint(hi) + 0x8000u) & 0xffff0000u;
  return uh | ul;
}

__device__ __forceinline__ unsigned short f2bf(float f) {
  return (unsigned short)((__float_as_uint(f) + 0x8000u) >> 16);
}

__device__ __forceinline__ float fast_tanh(float x) {
  float e = __expf(2.f * x);
  return 1.f - 2.f * __builtin_amdgcn_rcpf(e + 1.f);
}

// Direct HBM/L2 -> LDS DMA, 16B per lane. LDS dest is wave-uniform base + lane*16.
__device__ __forceinline__ void gload16(const void* g, void* l) {
  __builtin_amdgcn_global_load_lds(
      (const __attribute__((address_space(1))) unsigned char*)g,
      (__attribute__((address_space(3))) unsigned char*)l, 16, 0, 0);
}

// ---------------- K0: fused patient-mean + qpv/qps ----------------
__global__ __launch_bounds__(256) void k_qp(const float* __restrict__ query,
                                            const float* __restrict__ pat,
                                            const float* __restrict__ W1v,
                                            const float* __restrict__ W1s,
                                            const float* __restrict__ W3,
                                            const float* __restrict__ b3,
                                            float* __restrict__ qpv,
                                            float* __restrict__ qps) {
  __shared__ float pmL[DM_];
  const int t = threadIdx.x;
  const int b = blockIdx.x >> 1;
  for (int d = t; d < DM_; d += 256) {
    float s = 0.f;
    for (int l = 0; l < L_; ++l) s += pat[(b * L_ + l) * DM_ + d];
    pmL[d] = s * (1.f / 64.f);
  }
  __syncthreads();
  const int a = (blockIdx.x & 1) * 256 + t;
  float pi = b3[a];
  for (int d = 0; d < DM_; ++d) pi += pmL[d] * W3[d * ATT_ + a];
  float qv = 0.f, qs = 0.f;
  for (int h = 0; h < HID_; ++h) {
    float q = query[b * HID_ + h];
    qv += q * W1v[h * ATT_ + a];
    qs += q * W1s[h * ATT_ + a];
  }
  qpv[b * ATT_ + a] = qv + pi;
  qps[b * ATT_ + a] = qs + pi;
}

// ---------------- K0c: swizzle both W2 (K x 512 fp32) -> bf16 B-fragment order ---
// out block (kc,cb): [cb<8 per wave-col-group... global cb<32][q<4][n<16][j<8]
__global__ __launch_bounds__(256) void k_swz2(const float* __restrict__ W2v,
                                              const float* __restrict__ W2s,
                                              unsigned short* __restrict__ outV,
                                              unsigned short* __restrict__ outS) {
  int idx = blockIdx.x * 256 + threadIdx.x;
  const float* src;
  unsigned short* dst;
  if (idx < FEAT_ * ATT_) {
    src = W2v; dst = outV;
  } else {
    idx -= FEAT_ * ATT_;
    if (idx >= SEM_ * ATT_) return;
    src = W2s; dst = outS;
  }
  int k = idx >> 9, c = idx & 511;
  int kc = k >> 5, kr = k & 31, q = kr >> 3, j = kr & 7;
  int cb = c >> 4, n = c & 15;
  dst[(kc * 32 + cb) * 512 + q * 128 + n * 8 + j] = f2bf(src[idx]);
}

// ---------------- K1: fused score GEMM — both operands via LDS, counted vmcnt ----
// Block: 64 rows x 512 cols, 4 waves (wave w = cols w*128..+127, all 64 rows).
// THE R0-R3 invariant bottleneck: B was global-loaded and consumed per-iteration
// in the SAME in-order vmcnt queue as deep-prefetched A -> every B-consume wait
// force-retired the fresh A loads (effective depth 1, HBM latency exposed/iter).
// Fix: B consumed from LDS (lgkm domain), staged by global_load_lds dbuf;
// A reg-loaded depth-4 (static names), converted to bf16, ds_written 1 ahead.
// ONE counted s_waitcnt vmcnt(12)/iter retires exactly B(kc); A stays in flight.
__global__ __launch_bounds__(256, 2) void k_scores_fused(
    const float* __restrict__ X, const unsigned short* __restrict__ Wt,
    const float* __restrict__ qp, const float* __restrict__ vvec,
    float* __restrict__ score, int K, int rows_per_batch) {
  __shared__ __align__(16) char LdsA[2 * 4096];   // bf16 A tiles (swizzled)
  __shared__ __align__(16) char LdsB[2 * 32768];  // bf16 B tiles (fragment order)
  const int t = threadIdx.x;
  const int lane = t & 63, wave = t >> 6;
  const int quad = lane >> 4, l15 = lane & 15;
  const int row0 = blockIdx.x * 64;
  const int b = row0 / rows_per_batch;
  const int nk = K >> 5;

  // A global source: thread t -> row r = t>>2, k-offset (t&3)*8 (8 fp32 = 32B)
  const int r = t >> 2, q_ = t & 3;
  const float* gA = X + (size_t)(row0 + r) * K + q_ * 8;
  // A LDS write offset (bytes), XOR-swizzled: element (rb,q,m,j) at
  // rb*1024 + q*256 + (m^(q<<1))*16 + j*2
  const int awOff = (r >> 4) * 1024 + q_ * 256 + (((r & 15) ^ (q_ << 1)) << 4);
  // A LDS read offset for frag a: a*1024 + quad*256 + (l15^(quad<<1))*16
  const int arOff = quad * 256 + ((l15 ^ (quad << 1)) << 4);
  // B DMA: wave stages bytes [wave*8192, +8192) of each 32KB kc-tile
  const char* gBsrc = (const char*)Wt + (size_t)wave * 8192 + lane * 16;
  // B LDS read: frag j of this wave at wave*8192 + j*1024 + lane*16
  const int brOff = wave * 8192 + lane * 16;

  const f32x4 zero = {0.f, 0.f, 0.f, 0.f};
  f32x4 acc[4][8];
#pragma unroll
  for (int a = 0; a < 4; ++a)
#pragma unroll
    for (int cb = 0; cb < 8; ++cb) acc[a][cb] = zero;

  // ---- prologue ----
  f32x4 T0a = *(const f32x4*)(gA);          // tile 0
  f32x4 T0b = *(const f32x4*)(gA + 4);
  FENCE;
  {  // B-DMA tile 0 -> LdsB[0]
    char* dst = LdsB + wave * 8192;
#pragma unroll
    for (int i = 0; i < 8; ++i) gload16(gBsrc + i * 1024, dst + i * 1024);
  }
  FENCE;
  f32x4 A1a = *(const f32x4*)(gA + 32),  A1b = *(const f32x4*)(gA + 36);   // tile 1
  f32x4 A2a = *(const f32x4*)(gA + 64),  A2b = *(const f32x4*)(gA + 68);   // tile 2
  f32x4 A3a = *(const f32x4*)(gA + 96),  A3b = *(const f32x4*)(gA + 100);  // tile 3
  f32x4 A0a = *(const f32x4*)(gA + 128), A0b = *(const f32x4*)(gA + 132);  // tile 4
  FENCE;
  {  // convert tile 0, write Abuf[0]
    uint4 w;
    w.x = f2bf_pk(T0a.x, T0a.y); w.y = f2bf_pk(T0a.z, T0a.w);
    w.z = f2bf_pk(T0b.x, T0b.y); w.w = f2bf_pk(T0b.z, T0b.w);
    *(uint4*)(LdsA + awOff) = w;
  }
  // retire B(0) (the 8 A-set loads stay in flight); ds_write visible
  asm volatile("s_waitcnt lgkmcnt(0)\n\ts_waitcnt vmcnt(8)" ::: "memory");
  __builtin_amdgcn_s_barrier();
  FENCE;

  // ---- main loop: per kc, 2 barriers, one counted vmcnt(12) ----
#define STEP(KC, Pa, Pb)                                                       \
  {                                                                            \
    const int kc = (KC);                                                       \
    /* 1. convert tile kc+1 (loaded 4 iters ago), ds_write -> Abuf[(kc+1)&1] */\
    uint4 w;                                                                   \
    w.x = f2bf_pk(Pa.x, Pa.y); w.y = f2bf_pk(Pa.z, Pa.w);                      \
    w.z = f2bf_pk(Pb.x, Pb.y); w.w = f2bf_pk(Pb.z, Pb.w);                      \
    *(uint4*)(LdsA + ((kc + 1) & 1) * 4096 + awOff) = w;                       \
    FENCE;                                                                     \
    /* 2. B-DMA tile kc+1 -> LdsB[(kc+1)&1] (clamped; last write unread) */    \
    {                                                                          \
      const int kn = (kc + 1 < nk) ? kc + 1 : nk - 1;                          \
      const char* src = gBsrc + (size_t)kn * 32768;                            \
      char* dst = LdsB + ((kc + 1) & 1) * 32768 + wave * 8192;                 \
      _Pragma("unroll")                                                        \
      for (int i = 0; i < 8; ++i) gload16(src + i * 1024, dst + i * 1024);     \
    }                                                                          \
    FENCE;                                                                     \
    /* 3. A-load tile kc+5 (clamped) into the just-freed set */                \
    {                                                                          \
      const int kn5 = (kc + 5 < nk) ? kc + 5 : nk - 1;                         \
      Pa = *(const f32x4*)(gA + (size_t)kn5 * 32);                             \
      Pb = *(const f32x4*)(gA + (size_t)kn5 * 32 + 4);                         \
    }                                                                          \
    FENCE;                                                                     \
    /* 4. retire exactly B(kc): allow A(kc+4)2 + B(kc+1)8 + A(kc+5)2 = 12 */   \
    asm volatile("s_waitcnt lgkmcnt(0)\n\ts_waitcnt vmcnt(12)" ::: "memory");  \
    __builtin_amdgcn_s_barrier();                                              \
    FENCE;                                                                     \
    /* 5. ds_read frags from buf[kc&1], MFMA */                                \
    {                                                                          \
      const char* ab = LdsA + (kc & 1) * 4096;                                 \
      const char* bb = LdsB + (kc & 1) * 32768;                                \
      short8 af[4], bf8[8];                                                    \
      _Pragma("unroll")                                                        \
      for (int a = 0; a < 4; ++a) af[a] = *(const short8*)(ab + a * 1024 + arOff); \
      _Pragma("unroll")                                                        \
      for (int j = 0; j < 8; ++j) bf8[j] = *(const short8*)(bb + brOff + j * 1024); \
      __builtin_amdgcn_s_setprio(1);                                           \
      _Pragma("unroll")                                                        \
      for (int a = 0; a < 4; ++a)                                              \
        _Pragma("unroll")                                                      \
        for (int j = 0; j < 8; ++j)                                            \
          acc[a][j] = __builtin_amdgcn_mfma_f32_16x16x32_bf16(af[a], bf8[j], acc[a][j], 0, 0, 0); \
      __builtin_amdgcn_s_setprio(0);                                           \
    }                                                                          \
    FENCE;                                                                     \
    __builtin_amdgcn_s_barrier(); /* read-complete: protect next iter writes */\
    FENCE;                                                                     \
  }

  for (int kb = 0; kb < nk; kb += 4) {
    STEP(kb + 0, A1a, A1b);
    STEP(kb + 1, A2a, A2b);
    STEP(kb + 2, A3a, A3b);
    STEP(kb + 3, A0a, A0b);
  }
#undef STEP

  // ---- epilogue: per row, partial over this wave's 128 cols ----
  float qv_[8], vw_[8];
#pragma unroll
  for (int cb = 0; cb < 8; ++cb) {
    int col = wave * 128 + cb * 16 + l15;
    qv_[cb] = qp[b * ATT_ + col];
    vw_[cb] = vvec[col];
  }
#pragma unroll
  for (int a = 0; a < 4; ++a) {
#pragma unroll
    for (int rr = 0; rr < 4; ++rr) {
      float s = 0.f;
#pragma unroll
      for (int cb = 0; cb < 8; ++cb)
        s += fast_tanh(acc[a][cb][rr] + qv_[cb]) * vw_[cb];
      s += __shfl_xor(s, 1);
      s += __shfl_xor(s, 2);
      s += __shfl_xor(s, 4);
      s += __shfl_xor(s, 8);
      if (l15 == 0) atomicAdd(&score[row0 + a * 16 + quad * 4 + rr], s);
    }
  }
}

// ---------------- K2: softmax, both branches in one launch ----------------
__global__ __launch_bounds__(256) void k_softmax2(const float* __restrict__ scores_v,
                                                  const float* __restrict__ scores_s,
                                                  float* __restrict__ v_attn,
                                                  float* __restrict__ s_attn) {
  __shared__ float sm[4];
  const int bb = blockIdx.x, t = threadIdx.x;
  const float* s;
  float* dst;
  int N;
  if (bb < 32) { s = scores_v + (size_t)bb * NV_; dst = v_attn + (size_t)bb * NV_; N = NV_; }
  else         { s = scores_s + (size_t)(bb - 32) * NS_; dst = s_attn + (size_t)(bb - 32) * NS_; N = NS_; }
  float m = -1e30f;
  for (int i = t; i < N; i += 256) m = fmaxf(m, s[i]);
  for (int k = 32; k; k >>= 1) m = fmaxf(m, __shfl_xor(m, k));
  if ((t & 63) == 0) sm[t >> 6] = m;
  __syncthreads();
  m = fmaxf(fmaxf(sm[0], sm[1]), fmaxf(sm[2], sm[3]));
  __syncthreads();
  float sum = 0.f;
  for (int i = t; i < N; i += 256) sum += __expf(s[i] - m);
  for (int k = 32; k; k >>= 1) sum += __shfl_xor(sum, k);
  if ((t & 63) == 0) sm[t >> 6] = sum;
  __syncthreads();
  sum = sm[0] + sm[1] + sm[2] + sm[3];
  float inv = 1.f / sum;
  for (int i = t; i < N; i += 256) dst[i] = __expf(s[i] - m) * inv;
}

// ---------------- K3: fp32 weighted sum (both branches, atomics) ----------------
__global__ __launch_bounds__(256) void k_wsum2(const float* __restrict__ vf,
                                               const float* __restrict__ sf,
                                               const float* __restrict__ v_attn,
                                               const float* __restrict__ s_attn,
                                               float* __restrict__ ctx_pre) {
  const int b = blockIdx.x, y = blockIdx.y, t = threadIdx.x;
  const float* feats;
  const float* attn;
  int N, F, colOff, r0;
  if (y < 8) { feats = vf; attn = v_attn; N = NV_; F = FEAT_; colOff = 0;     r0 = y * 256; }
  else       { feats = sf; attn = s_attn; N = NS_; F = SEM_;  colOff = 1024;  r0 = (y - 8) * 256; }
  const int c4 = t * 4;
  if (c4 >= F) return;
  const float* fb = feats + ((size_t)b * N + r0) * F;
  const float* ab = attn + (size_t)b * N + r0;
  float4 acc = {0.f, 0.f, 0.f, 0.f};
#pragma unroll 4
  for (int r = 0; r < 256; ++r) {
    float a = ab[r];
    float4 v = *(const float4*)(fb + (size_t)r * F + c4);
    acc.x += a * v.x; acc.y += a * v.y; acc.z += a * v.z; acc.w += a * v.w;
  }
  float* dst = ctx_pre + b * 1536 + colOff + c4;
  atomicAdd(dst + 0, acc.x);
  atomicAdd(dst + 1, acc.y);
  atomicAdd(dst + 2, acc.z);
  atomicAdd(dst + 3, acc.w);
}

// ---------------- K4: ctx = ctx_pre @ W + bW ----------------
__global__ __launch_bounds__(256) void k_final(const float* __restrict__ cp,
                                               const float* __restrict__ W,
                                               const float* __restrict__ bW,
                                               float* __restrict__ out) {
  int b = blockIdx.x, oc = blockIdx.y, t = threadIdx.x;
  int o = oc * 256 + t;
  float acc = bW[o];
  const float* c = cp + b * 1536;
  for (int k = 0; k < 1536; ++k) acc += c[k] * W[k * FEAT_ + o];
  out[b * FEAT_ + o] = acc;
}

extern "C" void kernel_launch(void* const* d_in, const int* in_sizes, int n_in,
                              void* d_out, int out_size, void* d_ws, size_t ws_size,
                              hipStream_t stream) {
  const float* query = (const float*)d_in[0];
  const float* vf    = (const float*)d_in[1];
  const float* sf    = (const float*)d_in[2];
  const float* pat   = (const float*)d_in[3];
  const float* W1v   = (const float*)d_in[4];
  const float* W2v   = (const float*)d_in[5];
  const float* vv    = (const float*)d_in[6];
  const float* W3    = (const float*)d_in[7];
  const float* b3    = (const float*)d_in[8];
  const float* W1s   = (const float*)d_in[9];
  const float* W2s   = (const float*)d_in[10];
  const float* vs    = (const float*)d_in[11];
  const float* W     = (const float*)d_in[12];
  const float* bW    = (const float*)d_in[13];
  float* out = (float*)d_out;

  char* ws = (char*)d_ws;
  float* scores_v = (float*)(ws);                 // 256 KB
  float* scores_s = (float*)(ws + 262144);        // 64 KB
  float* ctx_pre  = (float*)(ws + 327680);        // 192 KB
  float* qpv      = (float*)(ws + 524288);        // 64 KB
  float* qps      = (float*)(ws + 589824);        // 64 KB
  unsigned short* Wtv = (unsigned short*)(ws + 655360);            // 1 MB
  unsigned short* Wts = (unsigned short*)(ws + 655360 + 1048576);  // 0.5 MB

  // zero scores + ctx_pre (atomic accumulation targets)
  hipMemsetAsync(d_ws, 0, 524288, stream);

  k_swz2<<<(FEAT_ * ATT_ + SEM_ * ATT_) / 256, 256, 0, stream>>>(W2v, W2s, Wtv, Wts);
  k_qp<<<64, 256, 0, stream>>>(query, pat, W1v, W1s, W3, b3, qpv, qps);

  float* v_attn = out + B_ * FEAT_;
  float* s_attn = out + B_ * FEAT_ + B_ * NV_;

  k_scores_fused<<<(B_ * NV_) / 64, 256, 0, stream>>>(vf, Wtv, qpv, vv, scores_v, FEAT_, NV_);
  k_scores_fused<<<(B_ * NS_) / 64, 256, 0, stream>>>(sf, Wts, qps, vs, scores_s, SEM_, NS_);
  k_softmax2<<<64, 256, 0, stream>>>(scores_v, scores_s, v_attn, s_attn);
  k_wsum2<<<dim3(B_, 10), 256, 0, stream>>>(vf, sf, v_attn, s_attn, ctx_pre);
  k_final<<<dim3(B_, 4), 256, 0, stream>>>(ctx_pre, W, bW, out);
}

// Round 5
// 633.666 us; speedup vs baseline: 1.0493x; 1.0493x over previous
//
#include <hip/hip_runtime.h>

typedef float f32x4 __attribute__((ext_vector_type(4)));
typedef short short8 __attribute__((ext_vector_type(8)));

// Problem constants
#define B_    32
#define NV_   2048
#define NS_   512
#define L_    64
#define FEAT_ 1024
#define SEM_  512
#define HID_  512
#define ATT_  512
#define DM_   512

#define FENCE asm volatile("" ::: "memory")

__device__ __forceinline__ unsigned int f2bf_pk(float lo, float hi) {
  unsigned int ul = (__float_as_uint(lo) + 0x8000u) >> 16;
  unsigned int uh = (__float_as_uint(hi) + 0x8000u) & 0xffff0000u;
  return uh | ul;
}

__device__ __forceinline__ unsigned short f2bf(float f) {
  return (unsigned short)((__float_as_uint(f) + 0x8000u) >> 16);
}

__device__ __forceinline__ float fast_tanh(float x) {
  float e = __expf(2.f * x);
  return 1.f - 2.f * __builtin_amdgcn_rcpf(e + 1.f);
}

// Direct HBM/L2 -> LDS DMA, 16B per lane. LDS dest is wave-uniform base + lane*16.
__device__ __forceinline__ void gload16(const void* g, void* l) {
  __builtin_amdgcn_global_load_lds(
      (const __attribute__((address_space(1))) unsigned char*)g,
      (__attribute__((address_space(3))) unsigned char*)l, 16, 0, 0);
}

// ---------------- K0: fused patient-mean + qpv/qps, 4x parallel ----------------
// grid 256: block = (b<<3)|aq. Block covers 64 a-cols; 4 wave-segments of 128 d/h
// each compute partials, cross-wave LDS reduce. (R4: 64 blocks, 1536-deep serial
// loops -> latency-bound on 1/4 of the CUs.)
__global__ __launch_bounds__(256) void k_qp(const float* __restrict__ query,
                                            const float* __restrict__ pat,
                                            const float* __restrict__ W1v,
                                            const float* __restrict__ W1s,
                                            const float* __restrict__ W3,
                                            const float* __restrict__ b3,
                                            float* __restrict__ qpv,
                                            float* __restrict__ qps) {
  __shared__ float pmL[DM_];
  __shared__ float red[3][4][64];
  const int t = threadIdx.x;
  const int b = blockIdx.x >> 3, aq = blockIdx.x & 7;
  for (int d = t; d < DM_; d += 256) {
    float s = 0.f;
    for (int l = 0; l < L_; ++l) s += pat[(b * L_ + l) * DM_ + d];
    pmL[d] = s * (1.f / 64.f);
  }
  __syncthreads();
  const int al = t & 63, seg = t >> 6;   // seg == wave
  const int a = aq * 64 + al;
  const int d0 = seg * 128;
  float pi = 0.f, qv = 0.f, qs = 0.f;
  for (int d = d0; d < d0 + 128; ++d) pi += pmL[d] * W3[d * ATT_ + a];
  for (int h = d0; h < d0 + 128; ++h) {
    float q = query[b * HID_ + h];
    qv += q * W1v[h * ATT_ + a];
    qs += q * W1s[h * ATT_ + a];
  }
  red[0][seg][al] = pi;
  red[1][seg][al] = qv;
  red[2][seg][al] = qs;
  __syncthreads();
  if (t < 64) {
    const int ao = aq * 64 + t;
    float p = red[0][0][t] + red[0][1][t] + red[0][2][t] + red[0][3][t] + b3[ao];
    float v = red[1][0][t] + red[1][1][t] + red[1][2][t] + red[1][3][t];
    float s = red[2][0][t] + red[2][1][t] + red[2][2][t] + red[2][3][t];
    qpv[b * ATT_ + ao] = v + p;
    qps[b * ATT_ + ao] = s + p;
  }
}

// ---------------- K0c: swizzle both W2 (K x 512 fp32) -> bf16 B-fragment order ---
__global__ __launch_bounds__(256) void k_swz2(const float* __restrict__ W2v,
                                              const float* __restrict__ W2s,
                                              unsigned short* __restrict__ outV,
                                              unsigned short* __restrict__ outS) {
  int idx = blockIdx.x * 256 + threadIdx.x;
  const float* src;
  unsigned short* dst;
  if (idx < FEAT_ * ATT_) {
    src = W2v; dst = outV;
  } else {
    idx -= FEAT_ * ATT_;
    if (idx >= SEM_ * ATT_) return;
    src = W2s; dst = outS;
  }
  int k = idx >> 9, c = idx & 511;
  int kc = k >> 5, kr = k & 31, q = kr >> 3, j = kr & 7;
  int cb = c >> 4, n = c & 15;
  dst[(kc * 32 + cb) * 512 + q * 128 + n * 8 + j] = f2bf(src[idx]);
}

// ---------------- K1: merged score GEMM (visual + semantic in one launch) -------
// Body identical to R4's verified counted-vmcnt pipeline; blockIdx selects branch
// (visual blocks 0..1023, semantic 1024..1279) so semantic work fills the CU tail.
__global__ __launch_bounds__(256, 2) void k_scores2(
    const float* __restrict__ vf, const float* __restrict__ sf,
    const unsigned short* __restrict__ Wtv, const unsigned short* __restrict__ Wts,
    const float* __restrict__ qpv, const float* __restrict__ qps,
    const float* __restrict__ vv, const float* __restrict__ vs,
    float* __restrict__ scores_v, float* __restrict__ scores_s) {
  __shared__ __align__(16) char LdsA[2 * 4096];   // bf16 A tiles (swizzled)
  __shared__ __align__(16) char LdsB[2 * 32768];  // bf16 B tiles (fragment order)
  const float* X;
  const unsigned short* Wt;
  const float* qp;
  const float* vvec;
  float* score;
  int K, rows_per_batch, row0;
  {
    int bid = blockIdx.x;
    if (bid < (B_ * NV_) / 64) {
      X = vf; Wt = Wtv; qp = qpv; vvec = vv; score = scores_v;
      K = FEAT_; rows_per_batch = NV_; row0 = bid * 64;
    } else {
      bid -= (B_ * NV_) / 64;
      X = sf; Wt = Wts; qp = qps; vvec = vs; score = scores_s;
      K = SEM_; rows_per_batch = NS_; row0 = bid * 64;
    }
  }
  const int t = threadIdx.x;
  const int lane = t & 63, wave = t >> 6;
  const int quad = lane >> 4, l15 = lane & 15;
  const int b = row0 / rows_per_batch;
  const int nk = K >> 5;

  // A global source: thread t -> row r = t>>2, k-offset (t&3)*8 (8 fp32 = 32B)
  const int r = t >> 2, q_ = t & 3;
  const float* gA = X + (size_t)(row0 + r) * K + q_ * 8;
  const int awOff = (r >> 4) * 1024 + q_ * 256 + (((r & 15) ^ (q_ << 1)) << 4);
  const int arOff = quad * 256 + ((l15 ^ (quad << 1)) << 4);
  const char* gBsrc = (const char*)Wt + (size_t)wave * 8192 + lane * 16;
  const int brOff = wave * 8192 + lane * 16;

  const f32x4 zero = {0.f, 0.f, 0.f, 0.f};
  f32x4 acc[4][8];
#pragma unroll
  for (int a = 0; a < 4; ++a)
#pragma unroll
    for (int cb = 0; cb < 8; ++cb) acc[a][cb] = zero;

  // ---- prologue ----
  f32x4 T0a = *(const f32x4*)(gA);          // tile 0
  f32x4 T0b = *(const f32x4*)(gA + 4);
  FENCE;
  {  // B-DMA tile 0 -> LdsB[0]
    char* dst = LdsB + wave * 8192;
#pragma unroll
    for (int i = 0; i < 8; ++i) gload16(gBsrc + i * 1024, dst + i * 1024);
  }
  FENCE;
  f32x4 A1a = *(const f32x4*)(gA + 32),  A1b = *(const f32x4*)(gA + 36);   // tile 1
  f32x4 A2a = *(const f32x4*)(gA + 64),  A2b = *(const f32x4*)(gA + 68);   // tile 2
  f32x4 A3a = *(const f32x4*)(gA + 96),  A3b = *(const f32x4*)(gA + 100);  // tile 3
  f32x4 A0a = *(const f32x4*)(gA + 128), A0b = *(const f32x4*)(gA + 132);  // tile 4
  FENCE;
  {  // convert tile 0, write Abuf[0]
    uint4 w;
    w.x = f2bf_pk(T0a.x, T0a.y); w.y = f2bf_pk(T0a.z, T0a.w);
    w.z = f2bf_pk(T0b.x, T0b.y); w.w = f2bf_pk(T0b.z, T0b.w);
    *(uint4*)(LdsA + awOff) = w;
  }
  asm volatile("s_waitcnt lgkmcnt(0)\n\ts_waitcnt vmcnt(8)" ::: "memory");
  __builtin_amdgcn_s_barrier();
  FENCE;

  // ---- main loop: per kc, 2 barriers, one counted vmcnt(12) ----
#define STEP(KC, Pa, Pb)                                                       \
  {                                                                            \
    const int kc = (KC);                                                       \
    uint4 w;                                                                   \
    w.x = f2bf_pk(Pa.x, Pa.y); w.y = f2bf_pk(Pa.z, Pa.w);                      \
    w.z = f2bf_pk(Pb.x, Pb.y); w.w = f2bf_pk(Pb.z, Pb.w);                      \
    *(uint4*)(LdsA + ((kc + 1) & 1) * 4096 + awOff) = w;                       \
    FENCE;                                                                     \
    {                                                                          \
      const int kn = (kc + 1 < nk) ? kc + 1 : nk - 1;                          \
      const char* src = gBsrc + (size_t)kn * 32768;                            \
      char* dst = LdsB + ((kc + 1) & 1) * 32768 + wave * 8192;                 \
      _Pragma("unroll")                                                        \
      for (int i = 0; i < 8; ++i) gload16(src + i * 1024, dst + i * 1024);     \
    }                                                                          \
    FENCE;                                                                     \
    {                                                                          \
      const int kn5 = (kc + 5 < nk) ? kc + 5 : nk - 1;                         \
      Pa = *(const f32x4*)(gA + (size_t)kn5 * 32);                             \
      Pb = *(const f32x4*)(gA + (size_t)kn5 * 32 + 4);                         \
    }                                                                          \
    FENCE;                                                                     \
    asm volatile("s_waitcnt lgkmcnt(0)\n\ts_waitcnt vmcnt(12)" ::: "memory");  \
    __builtin_amdgcn_s_barrier();                                              \
    FENCE;                                                                     \
    {                                                                          \
      const char* ab = LdsA + (kc & 1) * 4096;                                 \
      const char* bb = LdsB + (kc & 1) * 32768;                                \
      short8 af[4], bf8[8];                                                    \
      _Pragma("unroll")                                                        \
      for (int a = 0; a < 4; ++a) af[a] = *(const short8*)(ab + a * 1024 + arOff); \
      _Pragma("unroll")                                                        \
      for (int j = 0; j < 8; ++j) bf8[j] = *(const short8*)(bb + brOff + j * 1024); \
      __builtin_amdgcn_s_setprio(1);                                           \
      _Pragma("unroll")                                                        \
      for (int a = 0; a < 4; ++a)                                              \
        _Pragma("unroll")                                                      \
        for (int j = 0; j < 8; ++j)                                            \
          acc[a][j] = __builtin_amdgcn_mfma_f32_16x16x32_bf16(af[a], bf8[j], acc[a][j], 0, 0, 0); \
      __builtin_amdgcn_s_setprio(0);                                           \
    }                                                                          \
    FENCE;                                                                     \
    __builtin_amdgcn_s_barrier();                                              \
    FENCE;                                                                     \
  }

  for (int kb = 0; kb < nk; kb += 4) {
    STEP(kb + 0, A1a, A1b);
    STEP(kb + 1, A2a, A2b);
    STEP(kb + 2, A3a, A3b);
    STEP(kb + 3, A0a, A0b);
  }
#undef STEP

  // ---- epilogue: per row, partial over this wave's 128 cols ----
  float qv_[8], vw_[8];
#pragma unroll
  for (int cb = 0; cb < 8; ++cb) {
    int col = wave * 128 + cb * 16 + l15;
    qv_[cb] = qp[b * ATT_ + col];
    vw_[cb] = vvec[col];
  }
#pragma unroll
  for (int a = 0; a < 4; ++a) {
#pragma unroll
    for (int rr = 0; rr < 4; ++rr) {
      float s = 0.f;
#pragma unroll
      for (int cb = 0; cb < 8; ++cb)
        s += fast_tanh(acc[a][cb][rr] + qv_[cb]) * vw_[cb];
      s += __shfl_xor(s, 1);
      s += __shfl_xor(s, 2);
      s += __shfl_xor(s, 4);
      s += __shfl_xor(s, 8);
      if (l15 == 0) atomicAdd(&score[row0 + a * 16 + quad * 4 + rr], s);
    }
  }
}

// ---------------- K2: softmax, both branches in one launch ----------------
__global__ __launch_bounds__(256) void k_softmax2(const float* __restrict__ scores_v,
                                                  const float* __restrict__ scores_s,
                                                  float* __restrict__ v_attn,
                                                  float* __restrict__ s_attn) {
  __shared__ float sm[4];
  const int bb = blockIdx.x, t = threadIdx.x;
  const float* s;
  float* dst;
  int N;
  if (bb < 32) { s = scores_v + (size_t)bb * NV_; dst = v_attn + (size_t)bb * NV_; N = NV_; }
  else         { s = scores_s + (size_t)(bb - 32) * NS_; dst = s_attn + (size_t)(bb - 32) * NS_; N = NS_; }
  float m = -1e30f;
  for (int i = t; i < N; i += 256) m = fmaxf(m, s[i]);
  for (int k = 32; k; k >>= 1) m = fmaxf(m, __shfl_xor(m, k));
  if ((t & 63) == 0) sm[t >> 6] = m;
  __syncthreads();
  m = fmaxf(fmaxf(sm[0], sm[1]), fmaxf(sm[2], sm[3]));
  __syncthreads();
  float sum = 0.f;
  for (int i = t; i < N; i += 256) sum += __expf(s[i] - m);
  for (int k = 32; k; k >>= 1) sum += __shfl_xor(sum, k);
  if ((t & 63) == 0) sm[t >> 6] = sum;
  __syncthreads();
  sum = sm[0] + sm[1] + sm[2] + sm[3];
  float inv = 1.f / sum;
  for (int i = t; i < N; i += 256) dst[i] = __expf(s[i] - m) * inv;
}

// ---------------- K3: fp32 weighted sum, 4x parallel (64-row chunks) ----------
// grid (B_, 40): y<32 visual chunk (64 rows x 1024 cols, 256 threads = all cols);
// y>=32 semantic chunk (64 rows x 512 cols, thread halves split rows 0-31/32-63).
__global__ __launch_bounds__(256) void k_wsum2(const float* __restrict__ vf,
                                               const float* __restrict__ sf,
                                               const float* __restrict__ v_attn,
                                               const float* __restrict__ s_attn,
                                               float* __restrict__ ctx_pre) {
  const int b = blockIdx.x, y = blockIdx.y, t = threadIdx.x;
  const float* fb;
  const float* ab;
  int c4, colOff, rbeg, rend, F;
  if (y < 32) {
    const int r0 = y * 64;
    fb = vf + ((size_t)b * NV_ + r0) * FEAT_;
    ab = v_attn + (size_t)b * NV_ + r0;
    F = FEAT_; colOff = 0; c4 = t * 4; rbeg = 0; rend = 64;
  } else {
    const int r0 = (y - 32) * 64;
    fb = sf + ((size_t)b * NS_ + r0) * SEM_;
    ab = s_attn + (size_t)b * NS_ + r0;
    F = SEM_; colOff = 1024; c4 = (t & 127) * 4; rbeg = (t >> 7) * 32; rend = rbeg + 32;
  }
  float4 acc = {0.f, 0.f, 0.f, 0.f};
  for (int r = rbeg; r < rend; ++r) {
    float a = ab[r];
    float4 v = *(const float4*)(fb + (size_t)r * F + c4);
    acc.x += a * v.x; acc.y += a * v.y; acc.z += a * v.z; acc.w += a * v.w;
  }
  float* dst = ctx_pre + b * 1536 + colOff + c4;
  atomicAdd(dst + 0, acc.x);
  atomicAdd(dst + 1, acc.y);
  atomicAdd(dst + 2, acc.z);
  atomicAdd(dst + 3, acc.w);
}

// ---------------- K4: ctx = ctx_pre @ W + bW ----------------
__global__ __launch_bounds__(256) void k_final(const float* __restrict__ cp,
                                               const float* __restrict__ W,
                                               const float* __restrict__ bW,
                                               float* __restrict__ out) {
  int b = blockIdx.x, oc = blockIdx.y, t = threadIdx.x;
  int o = oc * 256 + t;
  float acc = bW[o];
  const float* c = cp + b * 1536;
  for (int k = 0; k < 1536; ++k) acc += c[k] * W[k * FEAT_ + o];
  out[b * FEAT_ + o] = acc;
}

extern "C" void kernel_launch(void* const* d_in, const int* in_sizes, int n_in,
                              void* d_out, int out_size, void* d_ws, size_t ws_size,
                              hipStream_t stream) {
  const float* query = (const float*)d_in[0];
  const float* vf    = (const float*)d_in[1];
  const float* sf    = (const float*)d_in[2];
  const float* pat   = (const float*)d_in[3];
  const float* W1v   = (const float*)d_in[4];
  const float* W2v   = (const float*)d_in[5];
  const float* vv    = (const float*)d_in[6];
  const float* W3    = (const float*)d_in[7];
  const float* b3    = (const float*)d_in[8];
  const float* W1s   = (const float*)d_in[9];
  const float* W2s   = (const float*)d_in[10];
  const float* vs    = (const float*)d_in[11];
  const float* W     = (const float*)d_in[12];
  const float* bW    = (const float*)d_in[13];
  float* out = (float*)d_out;

  char* ws = (char*)d_ws;
  float* scores_v = (float*)(ws);                 // 256 KB
  float* scores_s = (float*)(ws + 262144);        // 64 KB
  float* ctx_pre  = (float*)(ws + 327680);        // 192 KB
  float* qpv      = (float*)(ws + 524288);        // 64 KB
  float* qps      = (float*)(ws + 589824);        // 64 KB
  unsigned short* Wtv = (unsigned short*)(ws + 655360);            // 1 MB
  unsigned short* Wts = (unsigned short*)(ws + 655360 + 1048576);  // 0.5 MB

  // zero scores + ctx_pre (atomic accumulation targets)
  hipMemsetAsync(d_ws, 0, 524288, stream);

  k_swz2<<<(FEAT_ * ATT_ + SEM_ * ATT_) / 256, 256, 0, stream>>>(W2v, W2s, Wtv, Wts);
  k_qp<<<256, 256, 0, stream>>>(query, pat, W1v, W1s, W3, b3, qpv, qps);

  float* v_attn = out + B_ * FEAT_;
  float* s_attn = out + B_ * FEAT_ + B_ * NV_;

  k_scores2<<<(B_ * NV_) / 64 + (B_ * NS_) / 64, 256, 0, stream>>>(
      vf, sf, Wtv, Wts, qpv, qps, vv, vs, scores_v, scores_s);
  k_softmax2<<<64, 256, 0, stream>>>(scores_v, scores_s, v_attn, s_attn);
  k_wsum2<<<dim3(B_, 40), 256, 0, stream>>>(vf, sf, v_attn, s_attn, ctx_pre);
  k_final<<<dim3(B_, 4), 256, 0, stream>>>(ctx_pre, W, bW, out);
}